// Round 18
// baseline (78.694 us; speedup 1.0000x reference)
//
#include <hip/hip_runtime.h>
#include <math.h>

namespace {
constexpr int   NB   = 25;     // basis functions
constexpr int   TS   = 301;    // time steps
constexpr int   NTT  = 19;     // t-tiles of 16 (304)
constexpr float DT   = 0.01f;
constexpr float TAU  = 3.0f;
constexpr float AX   = 2.0f;
constexpr float AZ   = 48.0f;
constexpr float BZ   = 12.0f;  // AZ/4
constexpr int   BATCH = 65536;

typedef float  f32x4  __attribute__((ext_vector_type(4)));
typedef float  f32x4u __attribute__((ext_vector_type(4), aligned(4)));
typedef short  s16x8  __attribute__((ext_vector_type(8)));

__device__ inline ushort f2bf(float f) {           // RNE float->bf16
  uint u = __float_as_uint(f);
  uint r = u + 0x7fffu + ((u >> 16) & 1u);
  return (ushort)(r >> 16);
}
__device__ inline float bf2f(ushort h) {
  return __uint_as_float(((uint)h) << 16);
}
}

// ws layout (ushort8 records of 16B):
//   hi table: record[(d*NTT + tt)*64 + lane], 2432 records
//   lo table: follows at +2432 records.                 total 77,824 B
// Record (d,tt,lane): j=0..7 -> T[k = 8*(lane>>4)+j, t = tt*16 + (lane&15)]
//   T[5,t]=A_t, T[6,t]=B_t, T[7+i,t]=H_i[t]*scale[d*27+2+i], else 0.
__global__ __launch_bounds__(512)
void dmp_precompute(const float* __restrict__ c, const float* __restrict__ s2,
                    const float* __restrict__ scale, ushort* __restrict__ ws2) {
  __shared__ float gT[NB][304];     // TRANSPOSED basis: gT[n][t] (pad 304)
  __shared__ float H[NB + 2][304];
  __shared__ float cS[NB], vS[NB];
  const int tid = threadIdx.x;
  if (tid < NB) { cS[tid] = c[tid]; vS[tid] = s2[tid]; }
  __syncthreads();
  const float q = 1.0f - AX / TAU * DT;   // cx multiplier per step
  for (int i = tid; i < 304; i += 512) {
    if (i < TS) {
      float cx = powf(q, (float)(i + 1));   // cx updated BEFORE use in ref
      float p[NB]; float sum = 0.f;
      #pragma unroll
      for (int n = 0; n < NB; ++n) {
        float d = cx - cS[n];
        p[n] = expf(-0.5f * d * d / vS[n]);
        sum += p[n];
      }
      float m = cx / sum;
      #pragma unroll
      for (int n = 0; n < NB; ++n) gT[n][i] = p[n] * m;
    } else {
      #pragma unroll
      for (int n = 0; n < NB; ++n) gT[n][i] = 0.f;   // pad tail
    }
  }
  __syncthreads();
  // 27 independent linear-response recurrences (lanes 0..26).
  // R17 diagnosis: the old per-step ds_read of g[t][nn] serialized at
  // ~120cyc latency x 301 steps ~= 18us on ONE CU. Now: one ds_read_b128
  // per 4 steps, prefetched one vector ahead (latency hidden under the
  // ~100cyc arithmetic chain of 4 steps).
  if (tid < NB + 2) {
    float y, gl;
    if (tid == 0)      { y = 1.f; gl = 0.f; }   // response to y0
    else if (tid == 1) { y = 0.f; gl = 1.f; }   // response to goal
    else               { y = 0.f; gl = 0.f; }   // response to unit w_n
    float z = 0.f;
    const int nn = (tid >= 2) ? (tid - 2) : 0;
    const float msk = (tid >= 2) ? 1.f : 0.f;
    const float4* __restrict__ gp = (const float4*)&gT[nn][0];
    float4 gc = gp[0];
    for (int tb = 0; tb < TS; tb += 4) {
      const float4 gn = (tb + 4 < 304) ? gp[(tb >> 2) + 1]
                                       : float4{0.f, 0.f, 0.f, 0.f};
      #pragma unroll
      for (int j = 0; j < 4; ++j) {
        const int t = tb + j;
        if (t < TS) {
          const float fx = ((j == 0) ? gc.x : (j == 1) ? gc.y
                            : (j == 2) ? gc.z : gc.w) * msk;
          const float dy = z / TAU;
          const float dz = (AZ * (BZ * (gl - y) - z) + fx) / TAU;
          y += dy * DT;
          z += dz * DT;
          H[tid][t] = y;
        }
      }
      gc = gn;
    }
  }
  __syncthreads();
  constexpr int NREC = 2 * NTT * 64;   // 2432
  for (int rec = tid; rec < NREC; rec += 512) {
    const int d    = rec / (NTT * 64);
    const int rem  = rec - d * (NTT * 64);
    const int tt   = rem >> 6;
    const int lane = rem & 63;
    const int kb   = (lane >> 4) * 8;
    const int t    = tt * 16 + (lane & 15);
    ushort hi8[8], lo8[8];
    #pragma unroll
    for (int j = 0; j < 8; ++j) {
      const int k = kb + j;
      float v = 0.f;
      if (t < TS) {
        if (k == 5)                 v = H[0][t];
        else if (k == 6)            v = H[1][t];
        else if (k >= 7 && k <= 31) v = H[2 + (k - 7)][t] * scale[d * 27 + 2 + (k - 7)];
      }
      const ushort h = f2bf(v);
      hi8[j] = h;
      lo8[j] = f2bf(v - bf2f(h));
    }
    ushort* dst_h = ws2 + (size_t)rec * 8;
    ushort* dst_l = ws2 + (size_t)(NREC + rec) * 8;
    #pragma unroll
    for (int j = 0; j < 8; ++j) { dst_h[j] = hi8[j]; dst_l[j] = lo8[j]; }
  }
}

// MFMA GEMM, math == R14 (validated, absmax 0.031) with OPERANDS SWAPPED:
// table in the A slot, x-frag in the B slot. Fragment layouts make both
// per-lane register images identical to R14's (A[r,k]<->B[k,c] share the
// lane mapping), so ws2 and the x-build are unchanged; D comes out
// transposed: lane holds 4 CONSECUTIVE t of one out-row -> one dwordx4
// store per acc tile (19 store instrs/wave vs 76; 4 lanes/row merge to
// 64 B segments). No LDS, no barriers; (256,8) -> 32 waves/CU streaming.
__global__ __launch_bounds__(256, 8)
void dmp_mfma(const float* __restrict__ x, const float* __restrict__ scale,
              const ushort* __restrict__ ws2, float* __restrict__ out) {
  const int tid  = threadIdx.x;
  const int w    = tid >> 6;
  const int lane = tid & 63;
  const int d    = w & 1;
  const int rowb = blockIdx.x * 32 + (w >> 1) * 16;   // 16 batch-pairs
  const int m    = lane & 15;
  const int g    = lane >> 4;

  // ---- build x fragment (hi/lo); per-lane image same as R14 ----
  const float* __restrict__ xr = x + (size_t)(2 * (rowb + m) + d) * 27;
  const float y0s = xr[0] * scale[d * 27];
  const float gs  = xr[1] * scale[d * 27 + 1];
  const float dd  = gs - y0s;
  s16x8 Xh, Xl;
  #pragma unroll
  for (int j = 0; j < 8; ++j) {
    const int k   = 8 * g + j;
    const int idx = (k >= 7) ? (k - 5) : 0;      // clamp: no OOB
    const float wv = xr[idx] * dd;
    const float e  = (k < 5) ? 0.f : (k == 5) ? y0s : (k == 6) ? gs : wv;
    const ushort h = f2bf(e);
    Xh[j] = (short)h;
    Xl[j] = (short)f2bf(e - bf2f(h));
  }

  constexpr int NREC = 2 * NTT * 64;
  const s16x8* __restrict__ Th =
      (const s16x8*)ws2 + (size_t)(d * NTT) * 64 + lane;
  const s16x8* __restrict__ Tl = Th + NREC;

  // lane's out-row is fixed: batch-row rowb+m, dof d; t = tt*16 + 4g + j
  float* __restrict__ orow = out + (size_t)(2 * (rowb + m) + d) * TS;

  #pragma unroll 1
  for (int tt = 0; tt < NTT; ++tt) {
    const s16x8 th = Th[tt * 64];
    const s16x8 tl = Tl[tt * 64];
    f32x4 acc = {0.f, 0.f, 0.f, 0.f};
    acc = __builtin_amdgcn_mfma_f32_16x16x32_bf16(th, Xh, acc, 0, 0, 0);
    acc = __builtin_amdgcn_mfma_f32_16x16x32_bf16(tl, Xh, acc, 0, 0, 0);
    acc = __builtin_amdgcn_mfma_f32_16x16x32_bf16(th, Xl, acc, 0, 0, 0);
    const int t0 = tt * 16 + 4 * g;
    if (tt < NTT - 1) {
      *(f32x4u*)(orow + t0) = acc;               // 16 B, 4 consecutive t
    } else {
      if (g < 3)       *(f32x4u*)(orow + t0) = acc;
      else if (t0 < TS) orow[t0] = acc[0];       // t = 300 only
    }
  }
}

extern "C" void kernel_launch(void* const* d_in, const int* in_sizes, int n_in,
                              void* d_out, int out_size, void* d_ws, size_t ws_size,
                              hipStream_t stream) {
  const float* x  = (const float*)d_in[0];
  const float* c  = (const float*)d_in[1];
  const float* s2 = (const float*)d_in[2];
  const float* sc = (const float*)d_in[3];
  ushort* ws2 = (ushort*)d_ws;   // needs 77,824 bytes
  float* out = (float*)d_out;

  hipLaunchKernelGGL(dmp_precompute, dim3(1), dim3(512), 0, stream,
                     c, s2, sc, ws2);
  hipLaunchKernelGGL(dmp_mfma, dim3(BATCH / 32), dim3(256), 0, stream,
                     x, sc, ws2, out);
}

// Round 19
// 77.036 us; speedup vs baseline: 1.0215x; 1.0215x over previous
//
#include <hip/hip_runtime.h>
#include <math.h>

namespace {
constexpr int   NB   = 25;     // basis functions
constexpr int   TS   = 301;    // time steps
constexpr int   NTT  = 19;     // t-tiles of 16 (304)
constexpr float DT   = 0.01f;
constexpr float TAU  = 3.0f;
constexpr float AX   = 2.0f;
constexpr float AZ   = 48.0f;
constexpr float BZ   = 12.0f;  // AZ/4
constexpr int   BATCH = 65536;

typedef float  f32x4  __attribute__((ext_vector_type(4)));
typedef float  f32x4u __attribute__((ext_vector_type(4), aligned(4)));
typedef short  s16x8  __attribute__((ext_vector_type(8)));

__device__ inline ushort f2bf(float f) {           // RNE float->bf16
  uint u = __float_as_uint(f);
  uint r = u + 0x7fffu + ((u >> 16) & 1u);
  return (ushort)(r >> 16);
}
__device__ inline float bf2f(ushort h) {
  return __uint_as_float(((uint)h) << 16);
}
__device__ inline void mat3mul(float* R, const float* S) {  // R = R*S
  float T[9];
  #pragma unroll
  for (int i = 0; i < 3; ++i)
    #pragma unroll
    for (int j = 0; j < 3; ++j)
      T[3*i+j] = R[3*i+0]*S[0+j] + R[3*i+1]*S[3+j] + R[3*i+2]*S[6+j];
  #pragma unroll
  for (int i = 0; i < 9; ++i) R[i] = T[i];
}
}

// ws layout (ushort8 records of 16B):
//   hi table: record[(d*NTT + tt)*64 + lane], 2432 records
//   lo table: follows at +2432 records.                 total 77,824 B
// Record (d,tt,lane): j=0..7 -> T[k = 8*(lane>>4)+j, t = tt*16 + (lane&15)]
//   T[5,t]=A_t, T[6,t]=B_t, T[7+i,t]=H_i[t]*scale[d*27+2+i], else 0.
//
// R18 diagnosis: phase-2 was a 301-step SERIAL recurrence on one wave of
// one CU (dependent-LDS-read chain) adding its full time to every round.
// Replaced by closed form: step matrix N (3x3, goal-const augmented);
// A_t=[N^{t+1}]00, B_t=[N^{t+1}]02, P_k=[N^k]01; thread k computes N^k by
// binary exponentiation (no serial chain). H_n[t]=(DT/TAU)*conv(g_n,P)[t]
// as 475 register-blocked (n,chunk16) tasks: 256 FMA per 47 LDS reads,
// all indices compile-time (rule #20).
__global__ __launch_bounds__(512)
void dmp_precompute(const float* __restrict__ c, const float* __restrict__ s2,
                    const float* __restrict__ scale, ushort* __restrict__ ws2) {
  __shared__ float gT[NB][304];     // transposed basis, zero-padded tail
  __shared__ float H[NB + 2][304];  // [0]=A, [1]=B, [2+n]=H_n
  __shared__ float Pbuf[320];       // Pext = Pbuf+16; [0..15]=0 pad
  __shared__ float cS[NB], vS[NB];
  const int tid = threadIdx.x;
  if (tid < NB) { cS[tid] = c[tid]; vS[tid] = s2[tid]; }
  __syncthreads();

  // ---- phase 1: basis table gT[n][t] ----
  const float q = 1.0f - AX / TAU * DT;   // cx multiplier per step
  for (int i = tid; i < 304; i += 512) {
    if (i < TS) {
      float cx = powf(q, (float)(i + 1));   // cx updated BEFORE use in ref
      float p[NB]; float sum = 0.f;
      #pragma unroll
      for (int n = 0; n < NB; ++n) {
        float d = cx - cS[n];
        p[n] = expf(-0.5f * d * d / vS[n]);
        sum += p[n];
      }
      float m = cx / sum;
      #pragma unroll
      for (int n = 0; n < NB; ++n) gT[n][i] = p[n] * m;
    } else {
      #pragma unroll
      for (int n = 0; n < NB; ++n) gT[n][i] = 0.f;
    }
  }
  if (tid < 16) Pbuf[tid] = 0.f;             // negative-index pad
  if (tid >= 302 && tid < 304) Pbuf[16 + tid] = 0.f;  // tail pad

  // ---- phase 2: N^k via binary exponentiation (each thread) ----
  if (tid < 302) {
    const float a01 = DT / TAU;
    const float a10 = -AZ * BZ * DT / TAU;
    const float a11 = 1.0f - AZ * DT / TAU;
    const float b1  = AZ * BZ * DT / TAU;
    float Npow[9][9];                        // Npow[i] = N^(2^i)
    Npow[0][0]=1.f;  Npow[0][1]=a01; Npow[0][2]=0.f;
    Npow[0][3]=a10;  Npow[0][4]=a11; Npow[0][5]=b1;
    Npow[0][6]=0.f;  Npow[0][7]=0.f; Npow[0][8]=1.f;
    #pragma unroll
    for (int i = 1; i < 9; ++i) {
      #pragma unroll
      for (int e = 0; e < 9; ++e) Npow[i][e] = Npow[i - 1][e];
      mat3mul(Npow[i], Npow[i - 1]);
    }
    float R[9] = {1.f,0.f,0.f, 0.f,1.f,0.f, 0.f,0.f,1.f};
    #pragma unroll
    for (int i = 0; i < 9; ++i)
      if ((tid >> i) & 1) mat3mul(R, Npow[i]);
    if (tid <= 300) Pbuf[16 + tid] = R[1];   // P_k = [N^k]01
    if (tid >= 1) {                          // t = tid-1
      H[0][tid - 1] = R[0];                  // A_t = [N^{t+1}]00
      H[1][tid - 1] = R[2];                  // B_t = [N^{t+1}]02
    }
  }
  __syncthreads();

  // ---- phase 3: H_n[t] = (DT/TAU) * sum_j g_j[n] P[t-j] ----
  {
    const float sc_ = DT / TAU;
    const float* __restrict__ Pext = Pbuf + 16;
    const int idx = tid;                     // (n, chunk): 25*19 = 475
    if (idx < NB * NTT) {
      const int n  = idx / NTT;
      const int ch = idx - n * NTT;
      const int t0 = ch * 16;
      float acc[16];
      #pragma unroll
      for (int i = 0; i < 16; ++i) acc[i] = 0.f;
      for (int jb = 0; jb <= t0; jb += 16) {
        float gv[16], pv[31];
        #pragma unroll
        for (int jj = 0; jj < 16; ++jj) gv[jj] = gT[n][jb + jj];
        #pragma unroll
        for (int k = 0; k < 31; ++k) pv[k] = Pext[t0 - jb - 15 + k];
        #pragma unroll
        for (int i = 0; i < 16; ++i)
          #pragma unroll
          for (int jj = 0; jj < 16; ++jj)
            acc[i] = fmaf(gv[jj], pv[15 + i - jj], acc[i]);
      }
      #pragma unroll
      for (int i = 0; i < 16; ++i)
        if (t0 + i < TS) H[2 + n][t0 + i] = acc[i] * sc_;
    }
  }
  __syncthreads();

  // ---- phase 4: emit bf16 hi/lo records (unchanged) ----
  constexpr int NREC = 2 * NTT * 64;   // 2432
  for (int rec = tid; rec < NREC; rec += 512) {
    const int d    = rec / (NTT * 64);
    const int rem  = rec - d * (NTT * 64);
    const int tt   = rem >> 6;
    const int lane = rem & 63;
    const int kb   = (lane >> 4) * 8;
    const int t    = tt * 16 + (lane & 15);
    ushort hi8[8], lo8[8];
    #pragma unroll
    for (int j = 0; j < 8; ++j) {
      const int k = kb + j;
      float v = 0.f;
      if (t < TS) {
        if (k == 5)                 v = H[0][t];
        else if (k == 6)            v = H[1][t];
        else if (k >= 7 && k <= 31) v = H[2 + (k - 7)][t] * scale[d * 27 + 2 + (k - 7)];
      }
      const ushort h = f2bf(v);
      hi8[j] = h;
      lo8[j] = f2bf(v - bf2f(h));
    }
    ushort* dst_h = ws2 + (size_t)rec * 8;
    ushort* dst_l = ws2 + (size_t)(NREC + rec) * 8;
    #pragma unroll
    for (int j = 0; j < 8; ++j) { dst_h[j] = hi8[j]; dst_l[j] = lo8[j]; }
  }
}

// MFMA GEMM, math == R14/R18 (validated absmax 0.031), operands swapped:
// table in A slot, x-frag in B slot; lane holds 4 consecutive t of one
// out-row -> one dwordx4 store per acc tile. No LDS, no barriers.
__global__ __launch_bounds__(256, 8)
void dmp_mfma(const float* __restrict__ x, const float* __restrict__ scale,
              const ushort* __restrict__ ws2, float* __restrict__ out) {
  const int tid  = threadIdx.x;
  const int w    = tid >> 6;
  const int lane = tid & 63;
  const int d    = w & 1;
  const int rowb = blockIdx.x * 32 + (w >> 1) * 16;   // 16 batch-pairs
  const int m    = lane & 15;
  const int g    = lane >> 4;

  // ---- build x fragment (hi/lo) ----
  const float* __restrict__ xr = x + (size_t)(2 * (rowb + m) + d) * 27;
  const float y0s = xr[0] * scale[d * 27];
  const float gs  = xr[1] * scale[d * 27 + 1];
  const float dd  = gs - y0s;
  s16x8 Xh, Xl;
  #pragma unroll
  for (int j = 0; j < 8; ++j) {
    const int k   = 8 * g + j;
    const int idx = (k >= 7) ? (k - 5) : 0;      // clamp: no OOB
    const float wv = xr[idx] * dd;
    const float e  = (k < 5) ? 0.f : (k == 5) ? y0s : (k == 6) ? gs : wv;
    const ushort h = f2bf(e);
    Xh[j] = (short)h;
    Xl[j] = (short)f2bf(e - bf2f(h));
  }

  constexpr int NREC = 2 * NTT * 64;
  const s16x8* __restrict__ Th =
      (const s16x8*)ws2 + (size_t)(d * NTT) * 64 + lane;
  const s16x8* __restrict__ Tl = Th + NREC;

  float* __restrict__ orow = out + (size_t)(2 * (rowb + m) + d) * TS;

  #pragma unroll 1
  for (int tt = 0; tt < NTT; ++tt) {
    const s16x8 th = Th[tt * 64];
    const s16x8 tl = Tl[tt * 64];
    f32x4 acc = {0.f, 0.f, 0.f, 0.f};
    acc = __builtin_amdgcn_mfma_f32_16x16x32_bf16(th, Xh, acc, 0, 0, 0);
    acc = __builtin_amdgcn_mfma_f32_16x16x32_bf16(tl, Xh, acc, 0, 0, 0);
    acc = __builtin_amdgcn_mfma_f32_16x16x32_bf16(th, Xl, acc, 0, 0, 0);
    const int t0 = tt * 16 + 4 * g;
    if (tt < NTT - 1) {
      *(f32x4u*)(orow + t0) = acc;               // 16 B, 4 consecutive t
    } else {
      if (g < 3)       *(f32x4u*)(orow + t0) = acc;
      else if (t0 < TS) orow[t0] = acc[0];       // t = 300 only
    }
  }
}

extern "C" void kernel_launch(void* const* d_in, const int* in_sizes, int n_in,
                              void* d_out, int out_size, void* d_ws, size_t ws_size,
                              hipStream_t stream) {
  const float* x  = (const float*)d_in[0];
  const float* c  = (const float*)d_in[1];
  const float* s2 = (const float*)d_in[2];
  const float* sc = (const float*)d_in[3];
  ushort* ws2 = (ushort*)d_ws;   // needs 77,824 bytes
  float* out = (float*)d_out;

  hipLaunchKernelGGL(dmp_precompute, dim3(1), dim3(512), 0, stream,
                     c, s2, sc, ws2);
  hipLaunchKernelGGL(dmp_mfma, dim3(BATCH / 32), dim3(256), 0, stream,
                     x, sc, ws2, out);
}